// Round 1
// baseline (756.781 us; speedup 1.0000x reference)
//
#include <hip/hip_runtime.h>
#include <stdint.h>

// B=8 S=1024 D=1024 H=16 DK=64 DFF=4096
typedef float f32x4 __attribute__((ext_vector_type(4)));
typedef short short8 __attribute__((ext_vector_type(8)));
typedef __bf16 bf16x8 __attribute__((ext_vector_type(8)));

static __device__ __forceinline__ short f2bf(float f) {
  unsigned u = __builtin_bit_cast(unsigned, f);
  u = (u + 0x7FFFu + ((u >> 16) & 1u)) >> 16;
  return (short)u;
}

static __device__ __forceinline__ f32x4 mfma16(short8 a, short8 b, f32x4 c) {
  return __builtin_amdgcn_mfma_f32_16x16x32_bf16(
      __builtin_bit_cast(bf16x8, a), __builtin_bit_cast(bf16x8, b), c, 0, 0, 0);
}

static __device__ __forceinline__ void gld_lds16(const void* g, void* s) {
  __builtin_amdgcn_global_load_lds(
      (const __attribute__((address_space(1))) void*)g,
      (__attribute__((address_space(3))) void*)s, 16, 0, 0);
}

// ---------------- fp32 -> bf16 weight convert ----------------
__global__ __launch_bounds__(256) void cvt_f2bf(const float* __restrict__ in,
                                                short* __restrict__ out, int n4) {
  int i = blockIdx.x * 256 + threadIdx.x;
  if (i < n4) {
    float4 v = ((const float4*)in)[i];
    short4 o;
    o.x = f2bf(v.x); o.y = f2bf(v.y); o.z = f2bf(v.z); o.w = f2bf(v.w);
    ((short4*)out)[i] = o;
  }
}

// ---------------- mask pack: 32 int32 -> 1 bitword ----------------
__global__ __launch_bounds__(256) void packmask(const int* __restrict__ m,
                                                unsigned* __restrict__ out) {
  int w = blockIdx.x * 256 + threadIdx.x;  // 8*1024*32 words
  const int4* p = (const int4*)(m + (size_t)w * 32);
  unsigned bits = 0;
#pragma unroll
  for (int c = 0; c < 8; c++) {
    int4 v = p[c];
    bits |= (unsigned)(v.x != 0) << (c * 4 + 0);
    bits |= (unsigned)(v.y != 0) << (c * 4 + 1);
    bits |= (unsigned)(v.z != 0) << (c * 4 + 2);
    bits |= (unsigned)(v.w != 0) << (c * 4 + 3);
  }
  out[w] = bits;
}

// ---------------- LayerNorm (ddof=1, eps on std) fp32 -> bf16 ----------------
__global__ __launch_bounds__(256) void ln_bf16(const float* __restrict__ x,
                                               const float* __restrict__ g,
                                               const float* __restrict__ bb,
                                               short* __restrict__ out) {
  const int row = blockIdx.x, tid = threadIdx.x;
  const float4 xv = *(const float4*)&x[(size_t)row * 1024 + tid * 4];
  float s = xv.x + xv.y + xv.z + xv.w;
#pragma unroll
  for (int o = 32; o; o >>= 1) s += __shfl_down(s, o);
  __shared__ float red[8];
  if ((tid & 63) == 0) red[tid >> 6] = s;
  __syncthreads();
  const float mean = (red[0] + red[1] + red[2] + red[3]) * (1.f / 1024.f);
  const float a0 = xv.x - mean, a1 = xv.y - mean, a2 = xv.z - mean, a3 = xv.w - mean;
  float ss = a0 * a0 + a1 * a1 + a2 * a2 + a3 * a3;
#pragma unroll
  for (int o = 32; o; o >>= 1) ss += __shfl_down(ss, o);
  if ((tid & 63) == 0) red[4 + (tid >> 6)] = ss;
  __syncthreads();
  const float inv =
      1.f / (sqrtf((red[4] + red[5] + red[6] + red[7]) * (1.f / 1023.f)) + 1e-5f);
  const float4 gv = *(const float4*)&g[tid * 4];
  const float4 bv = *(const float4*)&bb[tid * 4];
  short4 o4;
  o4.x = f2bf(gv.x * a0 * inv + bv.x);
  o4.y = f2bf(gv.y * a1 * inv + bv.y);
  o4.z = f2bf(gv.z * a2 * inv + bv.z);
  o4.w = f2bf(gv.w * a3 * inv + bv.w);
  *(short4*)&out[(size_t)row * 1024 + tid * 4] = o4;
}

// ---------------- GEMM: C[M,N] = act(A[M,K] * Bw[N,K]^T + bias) (+resid) -----
// m97 structure: 128x128 tile, BK=32, 4 waves (2x2), global_load_lds width 16.
template <int ACT, int RES, int OBF>
__global__ __launch_bounds__(256) void gemm_bt(
    const short* __restrict__ A, const short* __restrict__ Bw,
    const float* __restrict__ bias, const float* __restrict__ resid,
    void* __restrict__ Cout, int M, int N, int K) {
  __shared__ alignas(1024) short As[128 * 32];
  __shared__ alignas(1024) short Bs[128 * 32];
  const int tid = threadIdx.x;
  const int l = tid & 63, w = tid >> 6;
  const int wr = w >> 1, wc = w & 1;
  const int m0 = blockIdx.y * 128, n0 = blockIdx.x * 128;
  const int fr = l & 15, fq = l >> 4;
  const size_t Ksz = (size_t)K;

  const short* ag = A + (size_t)(m0 + w * 32 + (l >> 2)) * Ksz + (l & 3) * 8;
  const short* bg = Bw + (size_t)(n0 + w * 32 + (l >> 2)) * Ksz + (l & 3) * 8;
  short* asw = As + w * 1024;  // wave-uniform LDS base (2KB/wave)
  short* bsw = Bs + w * 1024;

  f32x4 acc[4][4] = {};

  for (int kt = 0; kt < K; kt += 32) {
    gld_lds16(ag + kt, asw);
    gld_lds16(ag + kt + 16 * Ksz, asw + 512);
    gld_lds16(bg + kt, bsw);
    gld_lds16(bg + kt + 16 * Ksz, bsw + 512);
    __syncthreads();
    short8 af[4], bf[4];
#pragma unroll
    for (int m = 0; m < 4; m++)
      af[m] = *(const short8*)&As[(wr * 64 + m * 16 + fr) * 32 + fq * 8];
#pragma unroll
    for (int n = 0; n < 4; n++)
      bf[n] = *(const short8*)&Bs[(wc * 64 + n * 16 + fr) * 32 + fq * 8];
#pragma unroll
    for (int m = 0; m < 4; m++)
#pragma unroll
      for (int n = 0; n < 4; n++) acc[m][n] = mfma16(af[m], bf[n], acc[m][n]);
    __syncthreads();
  }

#pragma unroll
  for (int m = 0; m < 4; m++) {
#pragma unroll
    for (int n = 0; n < 4; n++) {
      const int row = m0 + wr * 64 + m * 16 + fq * 4;
      const int col = n0 + wc * 64 + n * 16 + fr;
      const float bvl = bias[col];
#pragma unroll
      for (int r = 0; r < 4; r++) {
        float v = acc[m][n][r] + bvl;
        if (ACT == 1) {  // tanh-GELU, overflow-safe via hw exp
          float zz = 0.7978845608028654f * (v + 0.044715f * v * v * v);
          float th = 1.f - 2.f / (__expf(2.f * zz) + 1.f);
          v = 0.5f * v * (1.f + th);
        }
        if (RES) v += resid[(size_t)(row + r) * N + col];
        if (OBF)
          ((short*)Cout)[(size_t)(row + r) * N + col] = f2bf(v);
        else
          ((float*)Cout)[(size_t)(row + r) * N + col] = v;
      }
    }
  }
}

// ---------------- flash attention (per block: b, h, 64 q-rows) ----------------
__global__ __launch_bounds__(256) void attn_fwd(const short* Qm,
                                                const short* __restrict__ Km,
                                                const short* __restrict__ Vm,
                                                const unsigned* __restrict__ MW,
                                                short* Om) {
  const int gid = blockIdx.x;
  const int qt = gid & 15;          // S/64
  const int h = (gid >> 4) & 15;    // H
  const int b = gid >> 8;           // B
  const int tid = threadIdx.x, l = tid & 63, w = tid >> 6;
  const int fr = l & 15, fq = l >> 4;
  __shared__ alignas(1024) short Ks[32 * 64];      // K tile [key][d]
  __shared__ alignas(1024) short Vt[64 * 32];      // V tile transposed [d][key]
  __shared__ alignas(1024) short Ps[4][16 * 32];   // per-wave P tile [q][key]
  const int qbase = qt * 64;

  short8 qf0, qf1;
  {
    const size_t qrow = (size_t)b * 1024 + qbase + w * 16 + fr;
    const short* qp = Qm + qrow * 1024 + h * 64 + fq * 8;
    qf0 = *(const short8*)qp;
    qf1 = *(const short8*)(qp + 32);
  }
  float mrun[4] = {-1e30f, -1e30f, -1e30f, -1e30f};
  float lrun[4] = {0.f, 0.f, 0.f, 0.f};
  f32x4 oacc[4] = {};

  const short* kg = Km + ((size_t)b * 1024 + w * 8 + (l >> 3)) * 1024 + h * 64 + (l & 7) * 8;
  const short* vg = Vm + ((size_t)b * 1024 + (tid >> 3)) * 1024 + h * 64 + (tid & 7) * 8;
  const unsigned* mwp = MW + ((size_t)b * 1024 + qbase + w * 16 + fq * 4) * 32;

  for (int kt = 0; kt < 32; kt++) {
    gld_lds16(kg + (size_t)kt * 32 * 1024, Ks + w * 512);
    short8 vv = *(const short8*)(vg + (size_t)kt * 32 * 1024);
#pragma unroll
    for (int j = 0; j < 8; j++) Vt[((tid & 7) * 8 + j) * 32 + (tid >> 3)] = vv[j];
    __syncthreads();

    const f32x4 z = {0.f, 0.f, 0.f, 0.f};
    short8 kf00 = *(const short8*)&Ks[fr * 64 + fq * 8];
    short8 kf01 = *(const short8*)&Ks[fr * 64 + 32 + fq * 8];
    short8 kf10 = *(const short8*)&Ks[(16 + fr) * 64 + fq * 8];
    short8 kf11 = *(const short8*)&Ks[(16 + fr) * 64 + 32 + fq * 8];
    f32x4 s0v = mfma16(qf0, kf00, z);
    s0v = mfma16(qf1, kf01, s0v);
    f32x4 s1v = mfma16(qf0, kf10, z);
    s1v = mfma16(qf1, kf11, s1v);

#pragma unroll
    for (int r = 0; r < 4; r++) {
      const unsigned mw = mwp[(size_t)r * 32 + kt];
      float s0 = s0v[r] * 0.125f;
      if (!((mw >> fr) & 1u)) s0 = -1e9f;
      float s1 = s1v[r] * 0.125f;
      if (!((mw >> (16 + fr)) & 1u)) s1 = -1e9f;
      float mx = fmaxf(s0, s1);
      mx = fmaxf(mx, __shfl_xor(mx, 1));
      mx = fmaxf(mx, __shfl_xor(mx, 2));
      mx = fmaxf(mx, __shfl_xor(mx, 4));
      mx = fmaxf(mx, __shfl_xor(mx, 8));
      const float nm = fmaxf(mrun[r], mx);
      const float al = __expf(mrun[r] - nm);
      const float p0 = __expf(s0 - nm);
      const float p1 = __expf(s1 - nm);
      float ts = p0 + p1;
      ts += __shfl_xor(ts, 1);
      ts += __shfl_xor(ts, 2);
      ts += __shfl_xor(ts, 4);
      ts += __shfl_xor(ts, 8);
      lrun[r] = lrun[r] * al + ts;
      mrun[r] = nm;
#pragma unroll
      for (int dt = 0; dt < 4; dt++) oacc[dt][r] *= al;
      Ps[w][(fq * 4 + r) * 32 + fr] = f2bf(p0);
      Ps[w][(fq * 4 + r) * 32 + 16 + fr] = f2bf(p1);
    }
    __syncthreads();
    short8 pa = *(const short8*)&Ps[w][fr * 32 + fq * 8];
#pragma unroll
    for (int dt = 0; dt < 4; dt++) {
      short8 vf = *(const short8*)&Vt[(dt * 16 + fr) * 32 + fq * 8];
      oacc[dt] = mfma16(pa, vf, oacc[dt]);
    }
    __syncthreads();
  }
#pragma unroll
  for (int dt = 0; dt < 4; dt++) {
#pragma unroll
    for (int r = 0; r < 4; r++) {
      const size_t qrow = (size_t)b * 1024 + qbase + w * 16 + fq * 4 + r;
      Om[qrow * 1024 + h * 64 + dt * 16 + fr] = f2bf(oacc[dt][r] / lrun[r]);
    }
  }
}

extern "C" void kernel_launch(void* const* d_in, const int* in_sizes, int n_in,
                              void* d_out, int out_size, void* d_ws, size_t ws_size,
                              hipStream_t stream) {
  (void)in_sizes; (void)n_in; (void)out_size; (void)ws_size;
  const float* x   = (const float*)d_in[0];
  const int*   msk = (const int*)d_in[1];
  const float* wq  = (const float*)d_in[2];
  const float* bq  = (const float*)d_in[3];
  const float* wk  = (const float*)d_in[4];
  const float* bk  = (const float*)d_in[5];
  const float* wv  = (const float*)d_in[6];
  const float* bv  = (const float*)d_in[7];
  const float* wo  = (const float*)d_in[8];
  const float* bo  = (const float*)d_in[9];
  const float* w1  = (const float*)d_in[10];
  const float* b1  = (const float*)d_in[11];
  const float* w2  = (const float*)d_in[12];
  const float* b2  = (const float*)d_in[13];
  const float* g1  = (const float*)d_in[14];
  const float* be1 = (const float*)d_in[15];
  const float* g2  = (const float*)d_in[16];
  const float* be2 = (const float*)d_in[17];
  float* out = (float*)d_out;

  char* p = (char*)d_ws;
  auto take = [&](size_t n) { char* r = p; p += (n + 1023) & ~(size_t)1023; return r; };
  const size_t MD = (size_t)8192 * 1024;
  short* XN = (short*)take(MD * 2);
  short* Qb = (short*)take(MD * 2);
  short* Kb = (short*)take(MD * 2);
  short* Vb = (short*)take(MD * 2);
  float* X1 = (float*)take(MD * 4);
  short* F1 = (short*)take((size_t)8192 * 4096 * 2);
  unsigned* MW = (unsigned*)take((size_t)8 * 1024 * 32 * 4);
  short* WQ = (short*)take((size_t)1024 * 1024 * 2);
  short* WK = (short*)take((size_t)1024 * 1024 * 2);
  short* WV = (short*)take((size_t)1024 * 1024 * 2);
  short* WO = (short*)take((size_t)1024 * 1024 * 2);
  short* W1 = (short*)take((size_t)4096 * 1024 * 2);
  short* W2 = (short*)take((size_t)1024 * 4096 * 2);

  cvt_f2bf<<<1024, 256, 0, stream>>>(wq, WQ, 262144);
  cvt_f2bf<<<1024, 256, 0, stream>>>(wk, WK, 262144);
  cvt_f2bf<<<1024, 256, 0, stream>>>(wv, WV, 262144);
  cvt_f2bf<<<1024, 256, 0, stream>>>(wo, WO, 262144);
  cvt_f2bf<<<4096, 256, 0, stream>>>(w1, W1, 1048576);
  cvt_f2bf<<<4096, 256, 0, stream>>>(w2, W2, 1048576);
  packmask<<<1024, 256, 0, stream>>>(msk, MW);
  ln_bf16<<<8192, 256, 0, stream>>>(x, g1, be1, XN);
  gemm_bt<0, 0, 1><<<dim3(8, 64), 256, 0, stream>>>(XN, WQ, bq, nullptr, Qb, 8192, 1024, 1024);
  gemm_bt<0, 0, 1><<<dim3(8, 64), 256, 0, stream>>>(XN, WK, bk, nullptr, Kb, 8192, 1024, 1024);
  gemm_bt<0, 0, 1><<<dim3(8, 64), 256, 0, stream>>>(XN, WV, bv, nullptr, Vb, 8192, 1024, 1024);
  attn_fwd<<<2048, 256, 0, stream>>>(Qb, Kb, Vb, MW, Qb);
  gemm_bt<0, 1, 0><<<dim3(8, 64), 256, 0, stream>>>(Qb, WO, bo, x, X1, 8192, 1024, 1024);
  ln_bf16<<<8192, 256, 0, stream>>>(X1, g2, be2, XN);
  gemm_bt<1, 0, 1><<<dim3(32, 64), 256, 0, stream>>>(XN, W1, b1, nullptr, F1, 8192, 4096, 1024);
  gemm_bt<0, 1, 0><<<dim3(8, 64), 256, 0, stream>>>(F1, W2, b2, X1, out, 8192, 1024, 4096);
}

// Round 2
// 664.825 us; speedup vs baseline: 1.1383x; 1.1383x over previous
//
#include <hip/hip_runtime.h>
#include <stdint.h>

// B=8 S=1024 D=1024 H=16 DK=64 DFF=4096
typedef float f32x4 __attribute__((ext_vector_type(4)));
typedef short short8 __attribute__((ext_vector_type(8)));
typedef __bf16 bf16x8 __attribute__((ext_vector_type(8)));

static __device__ __forceinline__ short f2bf(float f) {
  unsigned u = __builtin_bit_cast(unsigned, f);
  u = (u + 0x7FFFu + ((u >> 16) & 1u)) >> 16;
  return (short)u;
}

static __device__ __forceinline__ unsigned pack2bf(float a, float b) {
  return ((unsigned)(unsigned short)f2bf(a)) |
         (((unsigned)(unsigned short)f2bf(b)) << 16);
}

static __device__ __forceinline__ f32x4 mfma16(short8 a, short8 b, f32x4 c) {
  return __builtin_amdgcn_mfma_f32_16x16x32_bf16(
      __builtin_bit_cast(bf16x8, a), __builtin_bit_cast(bf16x8, b), c, 0, 0, 0);
}

static __device__ __forceinline__ void gld_lds16(const void* g, void* s) {
  __builtin_amdgcn_global_load_lds(
      (const __attribute__((address_space(1))) void*)g,
      (__attribute__((address_space(3))) void*)s, 16, 0, 0);
}

// ---------------- fp32 -> bf16 weight convert ----------------
__global__ __launch_bounds__(256) void cvt_f2bf(const float* __restrict__ in,
                                                short* __restrict__ out, int n4) {
  int i = blockIdx.x * 256 + threadIdx.x;
  if (i < n4) {
    float4 v = ((const float4*)in)[i];
    short4 o;
    o.x = f2bf(v.x); o.y = f2bf(v.y); o.z = f2bf(v.z); o.w = f2bf(v.w);
    ((short4*)out)[i] = o;
  }
}

// ---------------- mask pack: 32 int32 -> 1 bitword ----------------
__global__ __launch_bounds__(256) void packmask(const int* __restrict__ m,
                                                unsigned* __restrict__ out) {
  int w = blockIdx.x * 256 + threadIdx.x;  // 8*1024*32 words
  const int4* p = (const int4*)(m + (size_t)w * 32);
  unsigned bits = 0;
#pragma unroll
  for (int c = 0; c < 8; c++) {
    int4 v = p[c];
    bits |= (unsigned)(v.x != 0) << (c * 4 + 0);
    bits |= (unsigned)(v.y != 0) << (c * 4 + 1);
    bits |= (unsigned)(v.z != 0) << (c * 4 + 2);
    bits |= (unsigned)(v.w != 0) << (c * 4 + 3);
  }
  out[w] = bits;
}

// ---------------- LayerNorm (ddof=1, eps on std) fp32 -> bf16 ----------------
__global__ __launch_bounds__(256) void ln_bf16(const float* __restrict__ x,
                                               const float* __restrict__ g,
                                               const float* __restrict__ bb,
                                               short* __restrict__ out) {
  const int row = blockIdx.x, tid = threadIdx.x;
  const float4 xv = *(const float4*)&x[(size_t)row * 1024 + tid * 4];
  float s = xv.x + xv.y + xv.z + xv.w;
#pragma unroll
  for (int o = 32; o; o >>= 1) s += __shfl_down(s, o);
  __shared__ float red[8];
  if ((tid & 63) == 0) red[tid >> 6] = s;
  __syncthreads();
  const float mean = (red[0] + red[1] + red[2] + red[3]) * (1.f / 1024.f);
  const float a0 = xv.x - mean, a1 = xv.y - mean, a2 = xv.z - mean, a3 = xv.w - mean;
  float ss = a0 * a0 + a1 * a1 + a2 * a2 + a3 * a3;
#pragma unroll
  for (int o = 32; o; o >>= 1) ss += __shfl_down(ss, o);
  if ((tid & 63) == 0) red[4 + (tid >> 6)] = ss;
  __syncthreads();
  const float inv =
      1.f / (sqrtf((red[4] + red[5] + red[6] + red[7]) * (1.f / 1023.f)) + 1e-5f);
  const float4 gv = *(const float4*)&g[tid * 4];
  const float4 bv = *(const float4*)&bb[tid * 4];
  short4 o4;
  o4.x = f2bf(gv.x * a0 * inv + bv.x);
  o4.y = f2bf(gv.y * a1 * inv + bv.y);
  o4.z = f2bf(gv.z * a2 * inv + bv.z);
  o4.w = f2bf(gv.w * a3 * inv + bv.w);
  *(short4*)&out[(size_t)row * 1024 + tid * 4] = o4;
}

// ---------------- GEMM: C[M,N] = act(A[M,K] * Bw[N,K]^T + bias) (+resid) -----
template <int ACT, int RES, int OBF>
__global__ __launch_bounds__(256) void gemm_bt(
    const short* __restrict__ A, const short* __restrict__ Bw,
    const float* __restrict__ bias, const float* __restrict__ resid,
    void* __restrict__ Cout, int M, int N, int K) {
  __shared__ alignas(1024) short As[128 * 32];
  __shared__ alignas(1024) short Bs[128 * 32];
  const int tid = threadIdx.x;
  const int l = tid & 63, w = tid >> 6;
  const int wr = w >> 1, wc = w & 1;
  const int m0 = blockIdx.y * 128, n0 = blockIdx.x * 128;
  const int fr = l & 15, fq = l >> 4;
  const size_t Ksz = (size_t)K;

  const short* ag = A + (size_t)(m0 + w * 32 + (l >> 2)) * Ksz + (l & 3) * 8;
  const short* bg = Bw + (size_t)(n0 + w * 32 + (l >> 2)) * Ksz + (l & 3) * 8;
  short* asw = As + w * 1024;
  short* bsw = Bs + w * 1024;

  f32x4 acc[4][4] = {};

  for (int kt = 0; kt < K; kt += 32) {
    gld_lds16(ag + kt, asw);
    gld_lds16(ag + kt + 16 * Ksz, asw + 512);
    gld_lds16(bg + kt, bsw);
    gld_lds16(bg + kt + 16 * Ksz, bsw + 512);
    __syncthreads();
    short8 af[4], bf[4];
#pragma unroll
    for (int m = 0; m < 4; m++)
      af[m] = *(const short8*)&As[(wr * 64 + m * 16 + fr) * 32 + fq * 8];
#pragma unroll
    for (int n = 0; n < 4; n++)
      bf[n] = *(const short8*)&Bs[(wc * 64 + n * 16 + fr) * 32 + fq * 8];
#pragma unroll
    for (int m = 0; m < 4; m++)
#pragma unroll
      for (int n = 0; n < 4; n++) acc[m][n] = mfma16(af[m], bf[n], acc[m][n]);
    __syncthreads();
  }

#pragma unroll
  for (int m = 0; m < 4; m++) {
#pragma unroll
    for (int n = 0; n < 4; n++) {
      const int row = m0 + wr * 64 + m * 16 + fq * 4;
      const int col = n0 + wc * 64 + n * 16 + fr;
      const float bvl = bias[col];
#pragma unroll
      for (int r = 0; r < 4; r++) {
        float v = acc[m][n][r] + bvl;
        if (ACT == 1) {
          float zz = 0.7978845608028654f * (v + 0.044715f * v * v * v);
          float th = 1.f - 2.f / (__expf(2.f * zz) + 1.f);
          v = 0.5f * v * (1.f + th);
        }
        if (RES) v += resid[(size_t)(row + r) * N + col];
        if (OBF)
          ((short*)Cout)[(size_t)(row + r) * N + col] = f2bf(v);
        else
          ((float*)Cout)[(size_t)(row + r) * N + col] = v;
      }
    }
  }
}

// ---------------- flash attention v2 ----------------
// block = (b, h, 64 q rows); 4 waves x 16 q rows; KVBLK=64, dbuf K & V^T,
// XOR-swizzled LDS (slot ^= row&7 on 16B slots), per-wave P tile (no barrier),
// key-permuted P/V layout, defer-max softmax, 1 barrier/iter.
__global__ __launch_bounds__(256, 4) void attn_fwd(
    const short* __restrict__ Qm, const short* __restrict__ Km,
    const short* __restrict__ Vm, const unsigned* __restrict__ MW,
    short* __restrict__ Om) {
  const int orig = blockIdx.x;
  const int gid = (orig & 7) * 256 + (orig >> 3);  // XCD-contiguous chunks
  const int qt = gid & 15;
  const int h = (gid >> 4) & 15;
  const int b = gid >> 8;
  const int tid = threadIdx.x, l = tid & 63, w = tid >> 6;
  const int fr = l & 15, fq = l >> 4;
  __shared__ alignas(1024) short Ks[2][64 * 64];
  __shared__ alignas(1024) short Vt[2][64 * 64];
  __shared__ alignas(1024) short Ps[4][16 * 64];
  const int qbase = qt * 64;

  // Q fragments (A-frag: row = fr, k = slice*32 + fq*8)
  short8 qf0, qf1;
  {
    const short* qp = Qm + ((size_t)b * 1024 + qbase + w * 16 + fr) * 1024 + h * 64 + fq * 8;
    qf0 = *(const short8*)qp;
    qf1 = *(const short8*)(qp + 32);
  }
  f32x4 m2 = {-1e30f, -1e30f, -1e30f, -1e30f};
  f32x4 lsum = {};
  f32x4 oacc[4] = {};

  // K staging: wave w stages rows w*16..+15; pre-swizzled global source so the
  // linear global_load_lds dest yields LDS layout slot = c ^ (row&7).
  const int kcol = (l & 7) ^ ((l >> 3) & 7);
  const short* kg =
      Km + ((size_t)b * 1024 + w * 16 + (l >> 3)) * 1024 + h * 64 + kcol * 8;
  // V staging: lane loads key = w*16 + (l>>2), d = (l&3)*16 .. +15 (coalesced)
  const int vkey = w * 16 + (l >> 2), vd0 = (l & 3) * 16;
  const short* vg = Vm + ((size_t)b * 1024 + vkey) * 1024 + h * 64 + vd0;
  // permuted key index: tiles{0,1} -> fr*2+(j&1); tiles{2,3} -> 32+fr*2+(j&1)
  const int keyp = ((vkey >= 32) ? 32 : 0) + (l >> 2) * 2 + (w & 1);
  const int kslot = keyp >> 3, kbyte = keyp & 7;
  const unsigned* mwp = MW + ((size_t)b * 1024 + qbase + w * 16 + fq * 4) * 32;

  // prologue: stage tile 0
  gld_lds16(kg, &Ks[0][w * 1024]);
  gld_lds16(kg + 8 * 1024, &Ks[0][w * 1024 + 512]);
  short8 vv0 = *(const short8*)vg;
  short8 vv1 = *(const short8*)(vg + 8);
#pragma unroll
  for (int e = 0; e < 8; e++)
    Vt[0][(vd0 + e) * 64 + ((kslot ^ (e & 7)) << 3) + kbyte] = vv0[e];
#pragma unroll
  for (int e = 0; e < 8; e++)
    Vt[0][(vd0 + 8 + e) * 64 + ((kslot ^ (e & 7)) << 3) + kbyte] = vv1[e];
  __syncthreads();

  for (int t = 0; t < 16; t++) {
    const int cur = t & 1;
    if (t < 15) {
      const short* kgn = kg + (size_t)(t + 1) * 64 * 1024;
      gld_lds16(kgn, &Ks[cur ^ 1][w * 1024]);
      gld_lds16(kgn + 8 * 1024, &Ks[cur ^ 1][w * 1024 + 512]);
      const short* vgn = vg + (size_t)(t + 1) * 64 * 1024;
      vv0 = *(const short8*)vgn;
      vv1 = *(const short8*)(vgn + 8);
    }
    // QK^T: S[q=fq*4+r][key=j*16+fr]
    f32x4 sv[4];
    __builtin_amdgcn_s_setprio(1);
#pragma unroll
    for (int j = 0; j < 4; j++) {
      const int row = j * 16 + fr;
      short8 k0 = *(const short8*)&Ks[cur][row * 64 + ((fq ^ (fr & 7)) << 3)];
      short8 k1 = *(const short8*)&Ks[cur][row * 64 + (((4 + fq) ^ (fr & 7)) << 3)];
      f32x4 z = {0.f, 0.f, 0.f, 0.f};
      sv[j] = mfma16(qf0, k0, z);
      sv[j] = mfma16(qf1, k1, sv[j]);
    }
    __builtin_amdgcn_s_setprio(0);
    // softmax (defer-max)
#pragma unroll
    for (int r = 0; r < 4; r++) {
      const uint2 mw = *(const uint2*)(mwp + (size_t)r * 32 + t * 2);
      float t0 = ((mw.x >> fr) & 1u) ? sv[0][r] * 0.125f : -3e38f;
      float t1 = ((mw.x >> (16 + fr)) & 1u) ? sv[1][r] * 0.125f : -3e38f;
      float t2 = ((mw.y >> fr) & 1u) ? sv[2][r] * 0.125f : -3e38f;
      float t3 = ((mw.y >> (16 + fr)) & 1u) ? sv[3][r] * 0.125f : -3e38f;
      const float pmax = fmaxf(fmaxf(t0, t1), fmaxf(t2, t3));
      if (!__all(pmax <= m2[r] + 8.f)) {
        float mx = pmax;
        mx = fmaxf(mx, __shfl_xor(mx, 1));
        mx = fmaxf(mx, __shfl_xor(mx, 2));
        mx = fmaxf(mx, __shfl_xor(mx, 4));
        mx = fmaxf(mx, __shfl_xor(mx, 8));
        const float nm = fmaxf(m2[r], mx);
        const float al = __expf(m2[r] - nm);
        m2[r] = nm;
        lsum[r] *= al;
#pragma unroll
        for (int dt = 0; dt < 4; dt++) oacc[dt][r] *= al;
      }
      const float p0 = __expf(t0 - m2[r]);
      const float p1 = __expf(t1 - m2[r]);
      const float p2 = __expf(t2 - m2[r]);
      const float p3 = __expf(t3 - m2[r]);
      float ts = (p0 + p1) + (p2 + p3);
      ts += __shfl_xor(ts, 1);
      ts += __shfl_xor(ts, 2);
      ts += __shfl_xor(ts, 4);
      ts += __shfl_xor(ts, 8);
      lsum[r] += ts;
      const int q = fq * 4 + r;
      const int s0 = (fr >> 2) ^ (q & 7);
      const int s1 = (4 + (fr >> 2)) ^ (q & 7);
      *(unsigned*)&Ps[w][q * 64 + (s0 << 3) + ((fr & 3) << 1)] = pack2bf(p0, p1);
      *(unsigned*)&Ps[w][q * 64 + (s1 << 3) + ((fr & 3) << 1)] = pack2bf(p2, p3);
    }
    // PV: O[q][d] += P[q][k'] V^T[d][k']  (both sides share the key perm)
    short8 pa0 = *(const short8*)&Ps[w][fr * 64 + ((fq ^ (fr & 7)) << 3)];
    short8 pa1 = *(const short8*)&Ps[w][fr * 64 + (((4 + fq) ^ (fr & 7)) << 3)];
    __builtin_amdgcn_s_setprio(1);
#pragma unroll
    for (int dt = 0; dt < 4; dt++) {
      const int row = dt * 16 + fr;
      short8 v0 = *(const short8*)&Vt[cur][row * 64 + ((fq ^ (fr & 7)) << 3)];
      short8 v1 = *(const short8*)&Vt[cur][row * 64 + (((4 + fq) ^ (fr & 7)) << 3)];
      oacc[dt] = mfma16(pa0, v0, oacc[dt]);
      oacc[dt] = mfma16(pa1, v1, oacc[dt]);
    }
    __builtin_amdgcn_s_setprio(0);
    if (t < 15) {
#pragma unroll
      for (int e = 0; e < 8; e++)
        Vt[cur ^ 1][(vd0 + e) * 64 + ((kslot ^ (e & 7)) << 3) + kbyte] = vv0[e];
#pragma unroll
      for (int e = 0; e < 8; e++)
        Vt[cur ^ 1][(vd0 + 8 + e) * 64 + ((kslot ^ (e & 7)) << 3) + kbyte] = vv1[e];
    }
    __syncthreads();
  }

#pragma unroll
  for (int dt = 0; dt < 4; dt++) {
#pragma unroll
    for (int r = 0; r < 4; r++) {
      const size_t qrow = (size_t)b * 1024 + qbase + w * 16 + fq * 4 + r;
      Om[qrow * 1024 + h * 64 + dt * 16 + fr] = f2bf(oacc[dt][r] / lsum[r]);
    }
  }
}

extern "C" void kernel_launch(void* const* d_in, const int* in_sizes, int n_in,
                              void* d_out, int out_size, void* d_ws, size_t ws_size,
                              hipStream_t stream) {
  (void)in_sizes; (void)n_in; (void)out_size; (void)ws_size;
  const float* x   = (const float*)d_in[0];
  const int*   msk = (const int*)d_in[1];
  const float* wq  = (const float*)d_in[2];
  const float* bq  = (const float*)d_in[3];
  const float* wk  = (const float*)d_in[4];
  const float* bk  = (const float*)d_in[5];
  const float* wv  = (const float*)d_in[6];
  const float* bv  = (const float*)d_in[7];
  const float* wo  = (const float*)d_in[8];
  const float* bo  = (const float*)d_in[9];
  const float* w1  = (const float*)d_in[10];
  const float* b1  = (const float*)d_in[11];
  const float* w2  = (const float*)d_in[12];
  const float* b2  = (const float*)d_in[13];
  const float* g1  = (const float*)d_in[14];
  const float* be1 = (const float*)d_in[15];
  const float* g2  = (const float*)d_in[16];
  const float* be2 = (const float*)d_in[17];
  float* out = (float*)d_out;

  char* p = (char*)d_ws;
  auto take = [&](size_t n) { char* r = p; p += (n + 1023) & ~(size_t)1023; return r; };
  const size_t MD = (size_t)8192 * 1024;
  short* XN = (short*)take(MD * 2);
  short* Qb = (short*)take(MD * 2);
  short* Kb = (short*)take(MD * 2);
  short* Vb = (short*)take(MD * 2);
  float* X1 = (float*)take(MD * 4);
  short* F1 = (short*)take((size_t)8192 * 4096 * 2);
  unsigned* MW = (unsigned*)take((size_t)8 * 1024 * 32 * 4);
  short* WQ = (short*)take((size_t)1024 * 1024 * 2);
  short* WK = (short*)take((size_t)1024 * 1024 * 2);
  short* WV = (short*)take((size_t)1024 * 1024 * 2);
  short* WO = (short*)take((size_t)1024 * 1024 * 2);
  short* W1 = (short*)take((size_t)4096 * 1024 * 2);
  short* W2 = (short*)take((size_t)1024 * 4096 * 2);

  cvt_f2bf<<<1024, 256, 0, stream>>>(wq, WQ, 262144);
  cvt_f2bf<<<1024, 256, 0, stream>>>(wk, WK, 262144);
  cvt_f2bf<<<1024, 256, 0, stream>>>(wv, WV, 262144);
  cvt_f2bf<<<1024, 256, 0, stream>>>(wo, WO, 262144);
  cvt_f2bf<<<4096, 256, 0, stream>>>(w1, W1, 1048576);
  cvt_f2bf<<<4096, 256, 0, stream>>>(w2, W2, 1048576);
  packmask<<<1024, 256, 0, stream>>>(msk, MW);
  ln_bf16<<<8192, 256, 0, stream>>>(x, g1, be1, XN);
  gemm_bt<0, 0, 1><<<dim3(8, 64), 256, 0, stream>>>(XN, WQ, bq, nullptr, Qb, 8192, 1024, 1024);
  gemm_bt<0, 0, 1><<<dim3(8, 64), 256, 0, stream>>>(XN, WK, bk, nullptr, Kb, 8192, 1024, 1024);
  gemm_bt<0, 0, 1><<<dim3(8, 64), 256, 0, stream>>>(XN, WV, bv, nullptr, Vb, 8192, 1024, 1024);
  attn_fwd<<<2048, 256, 0, stream>>>(Qb, Kb, Vb, MW, Qb);
  gemm_bt<0, 1, 0><<<dim3(8, 64), 256, 0, stream>>>(Qb, WO, bo, x, X1, 8192, 1024, 1024);
  ln_bf16<<<8192, 256, 0, stream>>>(X1, g2, be2, XN);
  gemm_bt<1, 0, 1><<<dim3(32, 64), 256, 0, stream>>>(XN, W1, b1, nullptr, F1, 8192, 4096, 1024);
  gemm_bt<0, 1, 0><<<dim3(8, 64), 256, 0, stream>>>(F1, W2, b2, X1, out, 8192, 1024, 4096);
}

// Round 3
// 615.276 us; speedup vs baseline: 1.2300x; 1.0805x over previous
//
#include <hip/hip_runtime.h>
#include <stdint.h>

// B=8 S=1024 D=1024 H=16 DK=64 DFF=4096
typedef float f32x4 __attribute__((ext_vector_type(4)));
typedef short short8 __attribute__((ext_vector_type(8)));
typedef __bf16 bf16x8 __attribute__((ext_vector_type(8)));

static __device__ __forceinline__ short f2bf(float f) {
  unsigned u = __builtin_bit_cast(unsigned, f);
  u = (u + 0x7FFFu + ((u >> 16) & 1u)) >> 16;
  return (short)u;
}

static __device__ __forceinline__ float bf2f(short s) {
  return __builtin_bit_cast(float, (unsigned)((unsigned short)s) << 16);
}

static __device__ __forceinline__ unsigned pack2bf(float a, float b) {
  return ((unsigned)(unsigned short)f2bf(a)) |
         (((unsigned)(unsigned short)f2bf(b)) << 16);
}

static __device__ __forceinline__ f32x4 mfma16(short8 a, short8 b, f32x4 c) {
  return __builtin_amdgcn_mfma_f32_16x16x32_bf16(
      __builtin_bit_cast(bf16x8, a), __builtin_bit_cast(bf16x8, b), c, 0, 0, 0);
}

static __device__ __forceinline__ void gld_lds16(const void* g, void* s) {
  __builtin_amdgcn_global_load_lds(
      (const __attribute__((address_space(1))) void*)g,
      (__attribute__((address_space(3))) void*)s, 16, 0, 0);
}

// ---------------- fp32 -> bf16 weight convert ----------------
__global__ __launch_bounds__(256) void cvt_f2bf(const float* __restrict__ in,
                                                short* __restrict__ out, int n4) {
  int i = blockIdx.x * 256 + threadIdx.x;
  if (i < n4) {
    float4 v = ((const float4*)in)[i];
    short4 o;
    o.x = f2bf(v.x); o.y = f2bf(v.y); o.z = f2bf(v.z); o.w = f2bf(v.w);
    ((short4*)out)[i] = o;
  }
}

// ---------------- bias concat (1024+1024+1024 -> 3072) ----------------
__global__ __launch_bounds__(256) void concat3(const float* __restrict__ a,
                                               const float* __restrict__ b,
                                               const float* __restrict__ c,
                                               float* __restrict__ o) {
  int i = blockIdx.x * 256 + threadIdx.x;
  float v = (i < 1024) ? a[i] : ((i < 2048) ? b[i - 1024] : c[i - 2048]);
  o[i] = v;
}

// ---------------- mask pack: 32 int32 -> 1 bitword ----------------
__global__ __launch_bounds__(256) void packmask(const int* __restrict__ m,
                                                unsigned* __restrict__ out) {
  int w = blockIdx.x * 256 + threadIdx.x;
  const int4* p = (const int4*)(m + (size_t)w * 32);
  unsigned bits = 0;
#pragma unroll
  for (int c = 0; c < 8; c++) {
    int4 v = p[c];
    bits |= (unsigned)(v.x != 0) << (c * 4 + 0);
    bits |= (unsigned)(v.y != 0) << (c * 4 + 1);
    bits |= (unsigned)(v.z != 0) << (c * 4 + 2);
    bits |= (unsigned)(v.w != 0) << (c * 4 + 3);
  }
  out[w] = bits;
}

// ---------------- LayerNorm (ddof=1, eps on std) fp32 -> bf16 ----------------
__global__ __launch_bounds__(256) void ln_bf16(const float* __restrict__ x,
                                               const float* __restrict__ g,
                                               const float* __restrict__ bb,
                                               short* __restrict__ out) {
  const int row = blockIdx.x, tid = threadIdx.x;
  const float4 xv = *(const float4*)&x[(size_t)row * 1024 + tid * 4];
  float s = xv.x + xv.y + xv.z + xv.w;
#pragma unroll
  for (int o = 32; o; o >>= 1) s += __shfl_down(s, o);
  __shared__ float red[8];
  if ((tid & 63) == 0) red[tid >> 6] = s;
  __syncthreads();
  const float mean = (red[0] + red[1] + red[2] + red[3]) * (1.f / 1024.f);
  const float a0 = xv.x - mean, a1 = xv.y - mean, a2 = xv.z - mean, a3 = xv.w - mean;
  float ss = a0 * a0 + a1 * a1 + a2 * a2 + a3 * a3;
#pragma unroll
  for (int o = 32; o; o >>= 1) ss += __shfl_down(ss, o);
  if ((tid & 63) == 0) red[4 + (tid >> 6)] = ss;
  __syncthreads();
  const float inv =
      1.f / (sqrtf((red[4] + red[5] + red[6] + red[7]) * (1.f / 1023.f)) + 1e-5f);
  const float4 gv = *(const float4*)&g[tid * 4];
  const float4 bv = *(const float4*)&bb[tid * 4];
  short4 o4;
  o4.x = f2bf(gv.x * a0 * inv + bv.x);
  o4.y = f2bf(gv.y * a1 * inv + bv.y);
  o4.z = f2bf(gv.z * a2 * inv + bv.z);
  o4.w = f2bf(gv.w * a3 * inv + bv.w);
  *(short4*)&out[(size_t)row * 1024 + tid * 4] = o4;
}

// ---------------- GEMM: C[M,N] = act(A[M,K] * Bw[N,K]^T + bias) (+resid) -----
template <int ACT, int RES, int OBF>
__global__ __launch_bounds__(256) void gemm_bt(
    const short* __restrict__ A, const short* __restrict__ Bw,
    const float* __restrict__ bias, const float* __restrict__ resid,
    void* __restrict__ Cout, int M, int N, int K) {
  __shared__ alignas(1024) short As[128 * 32];
  __shared__ alignas(1024) short Bs[128 * 32];
  const int tid = threadIdx.x;
  const int l = tid & 63, w = tid >> 6;
  const int wr = w >> 1, wc = w & 1;
  const int m0 = blockIdx.y * 128, n0 = blockIdx.x * 128;
  const int fr = l & 15, fq = l >> 4;
  const size_t Ksz = (size_t)K;

  const short* ag = A + (size_t)(m0 + w * 32 + (l >> 2)) * Ksz + (l & 3) * 8;
  const short* bg = Bw + (size_t)(n0 + w * 32 + (l >> 2)) * Ksz + (l & 3) * 8;
  short* asw = As + w * 1024;
  short* bsw = Bs + w * 1024;

  f32x4 acc[4][4] = {};

  for (int kt = 0; kt < K; kt += 32) {
    gld_lds16(ag + kt, asw);
    gld_lds16(ag + kt + 16 * Ksz, asw + 512);
    gld_lds16(bg + kt, bsw);
    gld_lds16(bg + kt + 16 * Ksz, bsw + 512);
    __syncthreads();
    short8 af[4], bf[4];
#pragma unroll
    for (int m = 0; m < 4; m++)
      af[m] = *(const short8*)&As[(wr * 64 + m * 16 + fr) * 32 + fq * 8];
#pragma unroll
    for (int n = 0; n < 4; n++)
      bf[n] = *(const short8*)&Bs[(wc * 64 + n * 16 + fr) * 32 + fq * 8];
#pragma unroll
    for (int m = 0; m < 4; m++)
#pragma unroll
      for (int n = 0; n < 4; n++) acc[m][n] = mfma16(af[m], bf[n], acc[m][n]);
    __syncthreads();
  }

#pragma unroll
  for (int m = 0; m < 4; m++) {
#pragma unroll
    for (int n = 0; n < 4; n++) {
      const int row = m0 + wr * 64 + m * 16 + fq * 4;
      const int col = n0 + wc * 64 + n * 16 + fr;
      const float bvl = bias[col];
#pragma unroll
      for (int r = 0; r < 4; r++) {
        float v = acc[m][n][r] + bvl;
        if (ACT == 1) {
          float zz = 0.7978845608028654f * (v + 0.044715f * v * v * v);
          float th = 1.f - 2.f / (__expf(2.f * zz) + 1.f);
          v = 0.5f * v * (1.f + th);
        }
        if (RES) v += resid[(size_t)(row + r) * N + col];
        if (OBF)
          ((short*)Cout)[(size_t)(row + r) * N + col] = f2bf(v);
        else
          ((float*)Cout)[(size_t)(row + r) * N + col] = v;
      }
    }
  }
}

// ---------------- flash attention v3 ----------------
// Reads fused QKV [8192][3072] (Q|K|V column blocks). Per block: (b,h,64 q).
// V slot key = (row&7) ^ ((row>>4)<<1): spreads the 4 d-groups across bank
// halves on the transpose writes (was a 4-way conflict). Q pre-scaled by
// 1/8 (exact). lsum deferred to one end-of-kernel shuffle reduce.
__global__ __launch_bounds__(256, 4) void attn_fwd(
    const short* __restrict__ QKV, const unsigned* __restrict__ MW,
    short* __restrict__ Om) {
  const int orig = blockIdx.x;
  const int gid = (orig & 7) * 256 + (orig >> 3);  // bijective XCD swizzle
  const int qt = gid & 15;
  const int h = (gid >> 4) & 15;
  const int b = gid >> 8;
  const int tid = threadIdx.x, l = tid & 63, w = tid >> 6;
  const int fr = l & 15, fq = l >> 4;
  __shared__ alignas(1024) short Ks[2][64 * 64];
  __shared__ alignas(1024) short Vt[2][64 * 64];
  __shared__ alignas(1024) short Ps[4][16 * 64];
  const int qbase = qt * 64;
  const size_t RS = 3072;

  short8 qf0, qf1;
  {
    const short* qp =
        QKV + ((size_t)(b * 1024 + qbase + w * 16 + fr)) * RS + h * 64 + fq * 8;
    qf0 = *(const short8*)qp;
    qf1 = *(const short8*)(qp + 32);
#pragma unroll
    for (int e = 0; e < 8; e++) {  // exact pow2 scale: fold 1/sqrt(DK) into Q
      qf0[e] = f2bf(0.125f * bf2f(qf0[e]));
      qf1[e] = f2bf(0.125f * bf2f(qf1[e]));
    }
  }
  f32x4 m2 = {-1e30f, -1e30f, -1e30f, -1e30f};
  f32x4 lsum = {};
  f32x4 oacc[4] = {};

  const int kcol = (l & 7) ^ ((l >> 3) & 7);
  const short* kg =
      QKV + ((size_t)(b * 1024 + w * 16 + (l >> 3))) * RS + 1024 + h * 64 + kcol * 8;
  const int vkey = w * 16 + (l >> 2), vd0 = (l & 3) * 16;
  const short* vg = QKV + ((size_t)(b * 1024 + vkey)) * RS + 2048 + h * 64 + vd0;
  const int keyp = ((vkey >= 32) ? 32 : 0) + (l >> 2) * 2 + (w & 1);
  const int kslot = keyp >> 3, kbyte = keyp & 7;
  const int vxk = (l & 3) << 1;  // (row>>4)<<1 on the write side
  const unsigned* mwp = MW + ((size_t)(b * 1024 + qbase + w * 16 + fq * 4)) * 32;

  // prologue: stage tile 0
  gld_lds16(kg, &Ks[0][w * 1024]);
  gld_lds16(kg + 8 * RS, &Ks[0][w * 1024 + 512]);
  short8 vv0 = *(const short8*)vg;
  short8 vv1 = *(const short8*)(vg + 8);
#pragma unroll
  for (int e = 0; e < 8; e++)
    Vt[0][(vd0 + e) * 64 + ((kslot ^ (e & 7) ^ vxk) << 3) + kbyte] = vv0[e];
#pragma unroll
  for (int e = 0; e < 8; e++)
    Vt[0][(vd0 + 8 + e) * 64 + ((kslot ^ (e & 7) ^ vxk) << 3) + kbyte] = vv1[e];
  __syncthreads();

  for (int t = 0; t < 16; t++) {
    const int cur = t & 1;
    if (t < 15) {
      const short* kgn = kg + (size_t)(t + 1) * 64 * RS;
      gld_lds16(kgn, &Ks[cur ^ 1][w * 1024]);
      gld_lds16(kgn + 8 * RS, &Ks[cur ^ 1][w * 1024 + 512]);
      const short* vgn = vg + (size_t)(t + 1) * 64 * RS;
      vv0 = *(const short8*)vgn;
      vv1 = *(const short8*)(vgn + 8);
    }
    // QK^T
    f32x4 sv[4];
    __builtin_amdgcn_s_setprio(1);
#pragma unroll
    for (int j = 0; j < 4; j++) {
      const int row = j * 16 + fr;
      short8 k0 = *(const short8*)&Ks[cur][row * 64 + ((fq ^ (fr & 7)) << 3)];
      short8 k1 = *(const short8*)&Ks[cur][row * 64 + (((4 + fq) ^ (fr & 7)) << 3)];
      f32x4 z = {0.f, 0.f, 0.f, 0.f};
      sv[j] = mfma16(qf0, k0, z);
      sv[j] = mfma16(qf1, k1, sv[j]);
    }
    __builtin_amdgcn_s_setprio(0);
    // softmax (defer-max, deferred denominator)
#pragma unroll
    for (int r = 0; r < 4; r++) {
      const uint2 mw = *(const uint2*)(mwp + (size_t)r * 32 + t * 2);
      float t0 = ((mw.x >> fr) & 1u) ? sv[0][r] : -3e38f;
      float t1 = ((mw.x >> (16 + fr)) & 1u) ? sv[1][r] : -3e38f;
      float t2 = ((mw.y >> fr) & 1u) ? sv[2][r] : -3e38f;
      float t3 = ((mw.y >> (16 + fr)) & 1u) ? sv[3][r] : -3e38f;
      const float pmax = fmaxf(fmaxf(t0, t1), fmaxf(t2, t3));
      if (!__all(pmax <= m2[r] + 8.f)) {
        float mx = pmax;
        mx = fmaxf(mx, __shfl_xor(mx, 1));
        mx = fmaxf(mx, __shfl_xor(mx, 2));
        mx = fmaxf(mx, __shfl_xor(mx, 4));
        mx = fmaxf(mx, __shfl_xor(mx, 8));
        const float nm = fmaxf(m2[r], mx);
        const float al = __expf(m2[r] - nm);
        m2[r] = nm;
        lsum[r] *= al;
#pragma unroll
        for (int dt = 0; dt < 4; dt++) oacc[dt][r] *= al;
      }
      const float p0 = __expf(t0 - m2[r]);
      const float p1 = __expf(t1 - m2[r]);
      const float p2 = __expf(t2 - m2[r]);
      const float p3 = __expf(t3 - m2[r]);
      lsum[r] += (p0 + p1) + (p2 + p3);
      const int q = fq * 4 + r;
      const int s0 = (fr >> 2) ^ (q & 7);
      const int s1 = (4 + (fr >> 2)) ^ (q & 7);
      *(unsigned*)&Ps[w][q * 64 + (s0 << 3) + ((fr & 3) << 1)] = pack2bf(p0, p1);
      *(unsigned*)&Ps[w][q * 64 + (s1 << 3) + ((fr & 3) << 1)] = pack2bf(p2, p3);
    }
    // PV
    short8 pa0 = *(const short8*)&Ps[w][fr * 64 + ((fq ^ (fr & 7)) << 3)];
    short8 pa1 = *(const short8*)&Ps[w][fr * 64 + (((4 + fq) ^ (fr & 7)) << 3)];
    __builtin_amdgcn_s_setprio(1);
#pragma unroll
    for (int dt = 0; dt < 4; dt++) {
      const int row = dt * 16 + fr;
      const int vkx = dt << 1;  // (row>>4)<<1 on the read side
      short8 v0 = *(const short8*)&Vt[cur][row * 64 + ((fq ^ (fr & 7) ^ vkx) << 3)];
      short8 v1 =
          *(const short8*)&Vt[cur][row * 64 + (((4 + fq) ^ (fr & 7) ^ vkx) << 3)];
      oacc[dt] = mfma16(pa0, v0, oacc[dt]);
      oacc[dt] = mfma16(pa1, v1, oacc[dt]);
    }
    __builtin_amdgcn_s_setprio(0);
    if (t < 15) {
#pragma unroll
      for (int e = 0; e < 8; e++)
        Vt[cur ^ 1][(vd0 + e) * 64 + ((kslot ^ (e & 7) ^ vxk) << 3) + kbyte] = vv0[e];
#pragma unroll
      for (int e = 0; e < 8; e++)
        Vt[cur ^ 1][(vd0 + 8 + e) * 64 + ((kslot ^ (e & 7) ^ vxk) << 3) + kbyte] =
            vv1[e];
    }
    __syncthreads();
  }

  // end-of-kernel denominator reduce (16 lanes per q-row)
#pragma unroll
  for (int r = 0; r < 4; r++) {
    float s = lsum[r];
    s += __shfl_xor(s, 1);
    s += __shfl_xor(s, 2);
    s += __shfl_xor(s, 4);
    s += __shfl_xor(s, 8);
    lsum[r] = s;
  }

#pragma unroll
  for (int dt = 0; dt < 4; dt++) {
#pragma unroll
    for (int r = 0; r < 4; r++) {
      const size_t qrow = (size_t)b * 1024 + qbase + w * 16 + fq * 4 + r;
      Om[qrow * 1024 + h * 64 + dt * 16 + fr] = f2bf(oacc[dt][r] / lsum[r]);
    }
  }
}

extern "C" void kernel_launch(void* const* d_in, const int* in_sizes, int n_in,
                              void* d_out, int out_size, void* d_ws, size_t ws_size,
                              hipStream_t stream) {
  (void)in_sizes; (void)n_in; (void)out_size; (void)ws_size;
  const float* x   = (const float*)d_in[0];
  const int*   msk = (const int*)d_in[1];
  const float* wq  = (const float*)d_in[2];
  const float* bq  = (const float*)d_in[3];
  const float* wk  = (const float*)d_in[4];
  const float* bk  = (const float*)d_in[5];
  const float* wv  = (const float*)d_in[6];
  const float* bv  = (const float*)d_in[7];
  const float* wo  = (const float*)d_in[8];
  const float* bo  = (const float*)d_in[9];
  const float* w1  = (const float*)d_in[10];
  const float* b1  = (const float*)d_in[11];
  const float* w2  = (const float*)d_in[12];
  const float* b2  = (const float*)d_in[13];
  const float* g1  = (const float*)d_in[14];
  const float* be1 = (const float*)d_in[15];
  const float* g2  = (const float*)d_in[16];
  const float* be2 = (const float*)d_in[17];
  float* out = (float*)d_out;

  char* p = (char*)d_ws;
  auto take = [&](size_t n) { char* r = p; p += (n + 1023) & ~(size_t)1023; return r; };
  const size_t MD = (size_t)8192 * 1024;
  short* XN  = (short*)take(MD * 2);                      // 16MB
  short* BIG = (short*)take((size_t)8192 * 4096 * 2);     // 64MB: QKV then F1
  short* QKV = BIG;                                       // 8192 x 3072 (48MB)
  short* F1  = BIG;                                       // 8192 x 4096 (after attn)
  short* AO  = (short*)take(MD * 2);                      // 16MB attention output
  float* X1  = (float*)take(MD * 4);                      // 32MB
  unsigned* MW = (unsigned*)take((size_t)8 * 1024 * 32 * 4);
  short* WQKV = (short*)take((size_t)3072 * 1024 * 2);
  short* WO  = (short*)take((size_t)1024 * 1024 * 2);
  short* W1  = (short*)take((size_t)4096 * 1024 * 2);
  short* W2  = (short*)take((size_t)1024 * 4096 * 2);
  float* BQKV = (float*)take((size_t)3072 * 4);

  cvt_f2bf<<<1024, 256, 0, stream>>>(wq, WQKV, 262144);
  cvt_f2bf<<<1024, 256, 0, stream>>>(wk, WQKV + (size_t)1024 * 1024, 262144);
  cvt_f2bf<<<1024, 256, 0, stream>>>(wv, WQKV + (size_t)2048 * 1024, 262144);
  cvt_f2bf<<<1024, 256, 0, stream>>>(wo, WO, 262144);
  cvt_f2bf<<<4096, 256, 0, stream>>>(w1, W1, 1048576);
  cvt_f2bf<<<4096, 256, 0, stream>>>(w2, W2, 1048576);
  concat3<<<12, 256, 0, stream>>>(bq, bk, bv, BQKV);
  packmask<<<1024, 256, 0, stream>>>(msk, MW);
  ln_bf16<<<8192, 256, 0, stream>>>(x, g1, be1, XN);
  gemm_bt<0, 0, 1><<<dim3(24, 64), 256, 0, stream>>>(XN, WQKV, BQKV, nullptr, QKV,
                                                     8192, 3072, 1024);
  attn_fwd<<<2048, 256, 0, stream>>>(QKV, MW, AO);
  gemm_bt<0, 1, 0><<<dim3(8, 64), 256, 0, stream>>>(AO, WO, bo, x, X1, 8192, 1024, 1024);
  ln_bf16<<<8192, 256, 0, stream>>>(X1, g2, be2, XN);
  gemm_bt<1, 0, 1><<<dim3(32, 64), 256, 0, stream>>>(XN, W1, b1, nullptr, F1,
                                                     8192, 4096, 1024);
  gemm_bt<0, 1, 0><<<dim3(8, 64), 256, 0, stream>>>(F1, W2, b2, X1, out,
                                                    8192, 1024, 4096);
}

// Round 4
// 581.870 us; speedup vs baseline: 1.3006x; 1.0574x over previous
//
#include <hip/hip_runtime.h>
#include <stdint.h>

// B=8 S=1024 D=1024 H=16 DK=64 DFF=4096
typedef float f32x4 __attribute__((ext_vector_type(4)));
typedef short short8 __attribute__((ext_vector_type(8)));
typedef __bf16 bf16x8 __attribute__((ext_vector_type(8)));

static __device__ __forceinline__ short f2bf(float f) {
  unsigned u = __builtin_bit_cast(unsigned, f);
  u = (u + 0x7FFFu + ((u >> 16) & 1u)) >> 16;
  return (short)u;
}

static __device__ __forceinline__ float bf2f(short s) {
  return __builtin_bit_cast(float, (unsigned)((unsigned short)s) << 16);
}

static __device__ __forceinline__ unsigned pack2bf(float a, float b) {
  return ((unsigned)(unsigned short)f2bf(a)) |
         (((unsigned)(unsigned short)f2bf(b)) << 16);
}

static __device__ __forceinline__ f32x4 mfma16(short8 a, short8 b, f32x4 c) {
  return __builtin_amdgcn_mfma_f32_16x16x32_bf16(
      __builtin_bit_cast(bf16x8, a), __builtin_bit_cast(bf16x8, b), c, 0, 0, 0);
}

static __device__ __forceinline__ void gld_lds16(const void* g, void* s) {
  __builtin_amdgcn_global_load_lds(
      (const __attribute__((address_space(1))) void*)g,
      (__attribute__((address_space(3))) void*)s, 16, 0, 0);
}

#define BAR() asm volatile("s_barrier" ::: "memory")
#define VMW6() asm volatile("s_waitcnt vmcnt(6)" ::: "memory")
#define VMW0() asm volatile("s_waitcnt vmcnt(0)" ::: "memory")

// ---------------- fp32 -> bf16 weight convert ----------------
__global__ __launch_bounds__(256) void cvt_f2bf(const float* __restrict__ in,
                                                short* __restrict__ out, int n4) {
  int i = blockIdx.x * 256 + threadIdx.x;
  if (i < n4) {
    float4 v = ((const float4*)in)[i];
    short4 o;
    o.x = f2bf(v.x); o.y = f2bf(v.y); o.z = f2bf(v.z); o.w = f2bf(v.w);
    ((short4*)out)[i] = o;
  }
}

// ---------------- bias concat (1024+1024+1024 -> 3072) ----------------
__global__ __launch_bounds__(256) void concat3(const float* __restrict__ a,
                                               const float* __restrict__ b,
                                               const float* __restrict__ c,
                                               float* __restrict__ o) {
  int i = blockIdx.x * 256 + threadIdx.x;
  float v = (i < 1024) ? a[i] : ((i < 2048) ? b[i - 1024] : c[i - 2048]);
  o[i] = v;
}

// ---------------- mask pack: 32 int32 -> 1 bitword ----------------
__global__ __launch_bounds__(256) void packmask(const int* __restrict__ m,
                                                unsigned* __restrict__ out) {
  int w = blockIdx.x * 256 + threadIdx.x;
  const int4* p = (const int4*)(m + (size_t)w * 32);
  unsigned bits = 0;
#pragma unroll
  for (int c = 0; c < 8; c++) {
    int4 v = p[c];
    bits |= (unsigned)(v.x != 0) << (c * 4 + 0);
    bits |= (unsigned)(v.y != 0) << (c * 4 + 1);
    bits |= (unsigned)(v.z != 0) << (c * 4 + 2);
    bits |= (unsigned)(v.w != 0) << (c * 4 + 3);
  }
  out[w] = bits;
}

// ---------------- LayerNorm (ddof=1, eps on std) fp32 -> bf16 ----------------
__global__ __launch_bounds__(256) void ln_bf16(const float* __restrict__ x,
                                               const float* __restrict__ g,
                                               const float* __restrict__ bb,
                                               short* __restrict__ out) {
  const int row = blockIdx.x, tid = threadIdx.x;
  const float4 xv = *(const float4*)&x[(size_t)row * 1024 + tid * 4];
  float s = xv.x + xv.y + xv.z + xv.w;
#pragma unroll
  for (int o = 32; o; o >>= 1) s += __shfl_down(s, o);
  __shared__ float red[8];
  if ((tid & 63) == 0) red[tid >> 6] = s;
  __syncthreads();
  const float mean = (red[0] + red[1] + red[2] + red[3]) * (1.f / 1024.f);
  const float a0 = xv.x - mean, a1 = xv.y - mean, a2 = xv.z - mean, a3 = xv.w - mean;
  float ss = a0 * a0 + a1 * a1 + a2 * a2 + a3 * a3;
#pragma unroll
  for (int o = 32; o; o >>= 1) ss += __shfl_down(ss, o);
  if ((tid & 63) == 0) red[4 + (tid >> 6)] = ss;
  __syncthreads();
  const float inv =
      1.f / (sqrtf((red[4] + red[5] + red[6] + red[7]) * (1.f / 1023.f)) + 1e-5f);
  const float4 gv = *(const float4*)&g[tid * 4];
  const float4 bv = *(const float4*)&bb[tid * 4];
  short4 o4;
  o4.x = f2bf(gv.x * a0 * inv + bv.x);
  o4.y = f2bf(gv.y * a1 * inv + bv.y);
  o4.z = f2bf(gv.z * a2 * inv + bv.z);
  o4.w = f2bf(gv.w * a3 * inv + bv.w);
  *(short4*)&out[(size_t)row * 1024 + tid * 4] = o4;
}

// ---------------- 256x256 8-phase GEMM helpers ----------------
template <int MH>
static __device__ __forceinline__ void lda(short8 (&Af)[4][2], const short* As_,
                                           int fr, int fq) {
#pragma unroll
  for (int mm = 0; mm < 4; mm++)
#pragma unroll
    for (int kk = 0; kk < 2; kk++)
      Af[mm][kk] = *(const short8*)&As_[(MH * 64 + mm * 16 + fr) * 64 +
                                        (((kk * 4 + fq) ^ (fr & 7)) << 3)];
}

template <int NH>
static __device__ __forceinline__ void ldb(short8 (&Bf)[2][2], const short* Bs_,
                                           int brow0, int fr, int fq) {
#pragma unroll
  for (int nn = 0; nn < 2; nn++)
#pragma unroll
    for (int kk = 0; kk < 2; kk++)
      Bf[nn][kk] = *(const short8*)&Bs_[(brow0 + NH * 32 + nn * 16 + fr) * 64 +
                                        (((kk * 4 + fq) ^ (fr & 7)) << 3)];
}

template <int MH, int NH>
static __device__ __forceinline__ void mq(f32x4 (&acc)[8][4],
                                          const short8 (&Af)[4][2],
                                          const short8 (&Bf)[2][2]) {
  __builtin_amdgcn_s_setprio(1);
#pragma unroll
  for (int mm = 0; mm < 4; mm++)
#pragma unroll
    for (int nn = 0; nn < 2; nn++)
#pragma unroll
      for (int kk = 0; kk < 2; kk++)
        acc[MH * 4 + mm][NH * 2 + nn] =
            mfma16(Af[mm][kk], Bf[nn][kk], acc[MH * 4 + mm][NH * 2 + nn]);
  __builtin_amdgcn_s_setprio(0);
}

// ---------------- GEMM 256x256 tile, BK=64, 8 waves, 8-phase pipeline -------
// C[M,N] = act(A[M,K] * Bw[N,K]^T + bias) (+resid). LDS slot^=(row&7) swizzle
// (linear gld_lds dest + inverse-perm global source + swizzled ds_read).
// Counted vmcnt(6) only at phases 4/8; raw s_barrier (no vmcnt drain).
template <int ACT, int RES, int OBF>
__global__ __launch_bounds__(512, 2) void gemm256(
    const short* __restrict__ A, const short* __restrict__ Bw,
    const float* __restrict__ bias, const float* __restrict__ resid,
    void* __restrict__ Cout, int M, int N, int K) {
  extern __shared__ short smem[];  // [buf][A/B][half][128*64] = 128 KiB
  const int tid = threadIdx.x;
  const int l = tid & 63, w = tid >> 6;
  const int wr = w >> 2, wc = w & 3;
  const int fr = l & 15, fq = l >> 4;
  const int gx = gridDim.x;
  int flat = blockIdx.y * gx + blockIdx.x;
  {
    const int chunk = (gx * gridDim.y) >> 3;  // grids are %8==0
    flat = (flat & 7) * chunk + (flat >> 3);
  }
  const int m0 = (flat / gx) * 256, n0 = (flat % gx) * 256;
  const size_t Ksz = (size_t)K;
  const int NT = K >> 6;
  const int srow = tid >> 3;                       // 0..63
  const int gsw = ((tid & 7) ^ (srow & 7)) << 3;   // pre-swizzled col (elems)
  const int brow0 = (wc & 1) * 64;

  auto stage = [&](int bufi, int ab, int h, int s) {
    const short* gp = (ab ? Bw : A) +
                      (size_t)((ab ? n0 : m0) + h * 128 + srow) * Ksz + s * 64 + gsw;
    short* lp = smem + ((((bufi << 1) | ab) << 1) | h) * 8192 + w * 512;
    gld_lds16(gp, lp);
    gld_lds16(gp + (size_t)64 * Ksz, lp + 4096);
  };

  f32x4 acc[8][4] = {};
  short8 Af[4][2], Bf0[2][2], Bf1[2][2];

  // prologue: tile0 complete + tile1 {B0,B1,A0}; tile1.A1 staged at P1.
  stage(0, 0, 0, 0); stage(0, 0, 1, 0); stage(0, 1, 0, 0); stage(0, 1, 1, 0);
  stage(1, 1, 0, 1); stage(1, 1, 1, 1); stage(1, 0, 0, 1);
  VMW6();
  BAR();

  const short* As_;
  const short* Bs_;
  for (int t = 0; t < (NT >> 1); t++) {
    const int j1 = 2 * t + 1;
    int s0 = 2 * t + 2; if (s0 >= NT) s0 = NT - 2;
    int s1 = 2 * t + 3; if (s1 >= NT) s1 = NT - 1;

    // ---- K-tile 2t (buf0) ----
    As_ = smem + (0 * 4 + 0 * 2 + wr) * 8192;
    Bs_ = smem + (0 * 4 + 1 * 2 + (wc >> 1)) * 8192;
    // P1
    lda<0>(Af, As_, fr, fq); ldb<0>(Bf0, Bs_, brow0, fr, fq);
    stage(1, 0, 1, j1);
    BAR(); mq<0, 0>(acc, Af, Bf0); BAR();
    // P2
    ldb<1>(Bf1, Bs_, brow0, fr, fq);
    BAR(); mq<0, 1>(acc, Af, Bf1); BAR();
    // P3
    lda<1>(Af, As_, fr, fq);
    stage(0, 1, 0, s0);
    BAR(); mq<1, 1>(acc, Af, Bf1); BAR();
    // P4
    stage(0, 1, 1, s0); stage(0, 0, 0, s0);
    VMW6();
    BAR(); mq<1, 0>(acc, Af, Bf0); BAR();

    // ---- K-tile 2t+1 (buf1) ----
    As_ = smem + (1 * 4 + 0 * 2 + wr) * 8192;
    Bs_ = smem + (1 * 4 + 1 * 2 + (wc >> 1)) * 8192;
    // P5
    lda<0>(Af, As_, fr, fq); ldb<0>(Bf0, Bs_, brow0, fr, fq);
    stage(0, 0, 1, s0);
    BAR(); mq<0, 0>(acc, Af, Bf0); BAR();
    // P6
    ldb<1>(Bf1, Bs_, brow0, fr, fq);
    BAR(); mq<0, 1>(acc, Af, Bf1); BAR();
    // P7
    lda<1>(Af, As_, fr, fq);
    stage(1, 1, 0, s1);
    BAR(); mq<1, 1>(acc, Af, Bf1); BAR();
    // P8
    stage(1, 1, 1, s1); stage(1, 0, 0, s1);
    VMW6();
    BAR(); mq<1, 0>(acc, Af, Bf0); BAR();
  }
  VMW0();  // drain tail junk prefetches before wave exit

#pragma unroll
  for (int m = 0; m < 8; m++) {
#pragma unroll
    for (int n = 0; n < 4; n++) {
      const int row = m0 + wr * 128 + m * 16 + fq * 4;
      const int col = n0 + wc * 64 + n * 16 + fr;
      const float bvl = bias[col];
#pragma unroll
      for (int r = 0; r < 4; r++) {
        float v = acc[m][n][r] + bvl;
        if (ACT == 1) {
          float zz = 0.7978845608028654f * (v + 0.044715f * v * v * v);
          float th = 1.f - 2.f / (__expf(2.f * zz) + 1.f);
          v = 0.5f * v * (1.f + th);
        }
        if (RES) v += resid[(size_t)(row + r) * N + col];
        if (OBF)
          ((short*)Cout)[(size_t)(row + r) * N + col] = f2bf(v);
        else
          ((float*)Cout)[(size_t)(row + r) * N + col] = v;
      }
    }
  }
}

// ---------------- flash attention v3 (unchanged from R3) ----------------
__global__ __launch_bounds__(256, 4) void attn_fwd(
    const short* __restrict__ QKV, const unsigned* __restrict__ MW,
    short* __restrict__ Om) {
  const int orig = blockIdx.x;
  const int gid = (orig & 7) * 256 + (orig >> 3);
  const int qt = gid & 15;
  const int h = (gid >> 4) & 15;
  const int b = gid >> 8;
  const int tid = threadIdx.x, l = tid & 63, w = tid >> 6;
  const int fr = l & 15, fq = l >> 4;
  __shared__ alignas(1024) short Ks[2][64 * 64];
  __shared__ alignas(1024) short Vt[2][64 * 64];
  __shared__ alignas(1024) short Ps[4][16 * 64];
  const int qbase = qt * 64;
  const size_t RS = 3072;

  short8 qf0, qf1;
  {
    const short* qp =
        QKV + ((size_t)(b * 1024 + qbase + w * 16 + fr)) * RS + h * 64 + fq * 8;
    qf0 = *(const short8*)qp;
    qf1 = *(const short8*)(qp + 32);
#pragma unroll
    for (int e = 0; e < 8; e++) {
      qf0[e] = f2bf(0.125f * bf2f(qf0[e]));
      qf1[e] = f2bf(0.125f * bf2f(qf1[e]));
    }
  }
  f32x4 m2 = {-1e30f, -1e30f, -1e30f, -1e30f};
  f32x4 lsum = {};
  f32x4 oacc[4] = {};

  const int kcol = (l & 7) ^ ((l >> 3) & 7);
  const short* kg =
      QKV + ((size_t)(b * 1024 + w * 16 + (l >> 3))) * RS + 1024 + h * 64 + kcol * 8;
  const int vkey = w * 16 + (l >> 2), vd0 = (l & 3) * 16;
  const short* vg = QKV + ((size_t)(b * 1024 + vkey)) * RS + 2048 + h * 64 + vd0;
  const int keyp = ((vkey >= 32) ? 32 : 0) + (l >> 2) * 2 + (w & 1);
  const int kslot = keyp >> 3, kbyte = keyp & 7;
  const int vxk = (l & 3) << 1;
  const unsigned* mwp = MW + ((size_t)(b * 1024 + qbase + w * 16 + fq * 4)) * 32;

  gld_lds16(kg, &Ks[0][w * 1024]);
  gld_lds16(kg + 8 * RS, &Ks[0][w * 1024 + 512]);
  short8 vv0 = *(const short8*)vg;
  short8 vv1 = *(const short8*)(vg + 8);
#pragma unroll
  for (int e = 0; e < 8; e++)
    Vt[0][(vd0 + e) * 64 + ((kslot ^ (e & 7) ^ vxk) << 3) + kbyte] = vv0[e];
#pragma unroll
  for (int e = 0; e < 8; e++)
    Vt[0][(vd0 + 8 + e) * 64 + ((kslot ^ (e & 7) ^ vxk) << 3) + kbyte] = vv1[e];
  __syncthreads();

  for (int t = 0; t < 16; t++) {
    const int cur = t & 1;
    if (t < 15) {
      const short* kgn = kg + (size_t)(t + 1) * 64 * RS;
      gld_lds16(kgn, &Ks[cur ^ 1][w * 1024]);
      gld_lds16(kgn + 8 * RS, &Ks[cur ^ 1][w * 1024 + 512]);
      const short* vgn = vg + (size_t)(t + 1) * 64 * RS;
      vv0 = *(const short8*)vgn;
      vv1 = *(const short8*)(vgn + 8);
    }
    f32x4 sv[4];
    __builtin_amdgcn_s_setprio(1);
#pragma unroll
    for (int j = 0; j < 4; j++) {
      const int row = j * 16 + fr;
      short8 k0 = *(const short8*)&Ks[cur][row * 64 + ((fq ^ (fr & 7)) << 3)];
      short8 k1 = *(const short8*)&Ks[cur][row * 64 + (((4 + fq) ^ (fr & 7)) << 3)];
      f32x4 z = {0.f, 0.f, 0.f, 0.f};
      sv[j] = mfma16(qf0, k0, z);
      sv[j] = mfma16(qf1, k1, sv[j]);
    }
    __builtin_amdgcn_s_setprio(0);
#pragma unroll
    for (int r = 0; r < 4; r++) {
      const uint2 mw = *(const uint2*)(mwp + (size_t)r * 32 + t * 2);
      float t0 = ((mw.x >> fr) & 1u) ? sv[0][r] : -3e38f;
      float t1 = ((mw.x >> (16 + fr)) & 1u) ? sv[1][r] : -3e38f;
      float t2 = ((mw.y >> fr) & 1u) ? sv[2][r] : -3e38f;
      float t3 = ((mw.y >> (16 + fr)) & 1u) ? sv[3][r] : -3e38f;
      const float pmax = fmaxf(fmaxf(t0, t1), fmaxf(t2, t3));
      if (!__all(pmax <= m2[r] + 8.f)) {
        float mx = pmax;
        mx = fmaxf(mx, __shfl_xor(mx, 1));
        mx = fmaxf(mx, __shfl_xor(mx, 2));
        mx = fmaxf(mx, __shfl_xor(mx, 4));
        mx = fmaxf(mx, __shfl_xor(mx, 8));
        const float nm = fmaxf(m2[r], mx);
        const float al = __expf(m2[r] - nm);
        m2[r] = nm;
        lsum[r] *= al;
#pragma unroll
        for (int dt = 0; dt < 4; dt++) oacc[dt][r] *= al;
      }
      const float p0 = __expf(t0 - m2[r]);
      const float p1 = __expf(t1 - m2[r]);
      const float p2 = __expf(t2 - m2[r]);
      const float p3 = __expf(t3 - m2[r]);
      lsum[r] += (p0 + p1) + (p2 + p3);
      const int q = fq * 4 + r;
      const int s0 = (fr >> 2) ^ (q & 7);
      const int s1 = (4 + (fr >> 2)) ^ (q & 7);
      *(unsigned*)&Ps[w][q * 64 + (s0 << 3) + ((fr & 3) << 1)] = pack2bf(p0, p1);
      *(unsigned*)&Ps[w][q * 64 + (s1 << 3) + ((fr & 3) << 1)] = pack2bf(p2, p3);
    }
    short8 pa0 = *(const short8*)&Ps[w][fr * 64 + ((fq ^ (fr & 7)) << 3)];
    short8 pa1 = *(const short8*)&Ps[w][fr * 64 + (((4 + fq) ^ (fr & 7)) << 3)];
    __builtin_amdgcn_s_setprio(1);
#pragma unroll
    for (int dt = 0; dt < 4; dt++) {
      const int row = dt * 16 + fr;
      const int vkx = dt << 1;
      short8 v0 = *(const short8*)&Vt[cur][row * 64 + ((fq ^ (fr & 7) ^ vkx) << 3)];
      short8 v1 =
          *(const short8*)&Vt[cur][row * 64 + (((4 + fq) ^ (fr & 7) ^ vkx) << 3)];
      oacc[dt] = mfma16(pa0, v0, oacc[dt]);
      oacc[dt] = mfma16(pa1, v1, oacc[dt]);
    }
    __builtin_amdgcn_s_setprio(0);
    if (t < 15) {
#pragma unroll
      for (int e = 0; e < 8; e++)
        Vt[cur ^ 1][(vd0 + e) * 64 + ((kslot ^ (e & 7) ^ vxk) << 3) + kbyte] = vv0[e];
#pragma unroll
      for (int e = 0; e < 8; e++)
        Vt[cur ^ 1][(vd0 + 8 + e) * 64 + ((kslot ^ (e & 7) ^ vxk) << 3) + kbyte] =
            vv1[e];
    }
    __syncthreads();
  }

#pragma unroll
  for (int r = 0; r < 4; r++) {
    float s = lsum[r];
    s += __shfl_xor(s, 1);
    s += __shfl_xor(s, 2);
    s += __shfl_xor(s, 4);
    s += __shfl_xor(s, 8);
    lsum[r] = s;
  }

#pragma unroll
  for (int dt = 0; dt < 4; dt++) {
#pragma unroll
    for (int r = 0; r < 4; r++) {
      const size_t qrow = (size_t)b * 1024 + qbase + w * 16 + fq * 4 + r;
      Om[qrow * 1024 + h * 64 + dt * 16 + fr] = f2bf(oacc[dt][r] / lsum[r]);
    }
  }
}

extern "C" void kernel_launch(void* const* d_in, const int* in_sizes, int n_in,
                              void* d_out, int out_size, void* d_ws, size_t ws_size,
                              hipStream_t stream) {
  (void)in_sizes; (void)n_in; (void)out_size; (void)ws_size;
  const float* x   = (const float*)d_in[0];
  const int*   msk = (const int*)d_in[1];
  const float* wq  = (const float*)d_in[2];
  const float* bq  = (const float*)d_in[3];
  const float* wk  = (const float*)d_in[4];
  const float* bk  = (const float*)d_in[5];
  const float* wv  = (const float*)d_in[6];
  const float* bv  = (const float*)d_in[7];
  const float* wo  = (const float*)d_in[8];
  const float* bo  = (const float*)d_in[9];
  const float* w1  = (const float*)d_in[10];
  const float* b1  = (const float*)d_in[11];
  const float* w2  = (const float*)d_in[12];
  const float* b2  = (const float*)d_in[13];
  const float* g1  = (const float*)d_in[14];
  const float* be1 = (const float*)d_in[15];
  const float* g2  = (const float*)d_in[16];
  const float* be2 = (const float*)d_in[17];
  float* out = (float*)d_out;

  char* p = (char*)d_ws;
  auto take = [&](size_t n) { char* r = p; p += (n + 1023) & ~(size_t)1023; return r; };
  const size_t MD = (size_t)8192 * 1024;
  short* XN  = (short*)take(MD * 2);
  short* BIG = (short*)take((size_t)8192 * 4096 * 2);  // QKV then F1
  short* QKV = BIG;
  short* F1  = BIG;
  short* AO  = (short*)take(MD * 2);
  float* X1  = (float*)take(MD * 4);
  unsigned* MW = (unsigned*)take((size_t)8 * 1024 * 32 * 4);
  short* WQKV = (short*)take((size_t)3072 * 1024 * 2);
  short* WO  = (short*)take((size_t)1024 * 1024 * 2);
  short* W1  = (short*)take((size_t)4096 * 1024 * 2);
  short* W2  = (short*)take((size_t)1024 * 4096 * 2);
  float* BQKV = (float*)take((size_t)3072 * 4);

  const int SMEM = 131072;
  hipFuncSetAttribute((const void*)gemm256<0, 0, 1>,
                      hipFuncAttributeMaxDynamicSharedMemorySize, SMEM);
  hipFuncSetAttribute((const void*)gemm256<0, 1, 0>,
                      hipFuncAttributeMaxDynamicSharedMemorySize, SMEM);
  hipFuncSetAttribute((const void*)gemm256<1, 0, 1>,
                      hipFuncAttributeMaxDynamicSharedMemorySize, SMEM);

  cvt_f2bf<<<1024, 256, 0, stream>>>(wq, WQKV, 262144);
  cvt_f2bf<<<1024, 256, 0, stream>>>(wk, WQKV + (size_t)1024 * 1024, 262144);
  cvt_f2bf<<<1024, 256, 0, stream>>>(wv, WQKV + (size_t)2048 * 1024, 262144);
  cvt_f2bf<<<1024, 256, 0, stream>>>(wo, WO, 262144);
  cvt_f2bf<<<4096, 256, 0, stream>>>(w1, W1, 1048576);
  cvt_f2bf<<<4096, 256, 0, stream>>>(w2, W2, 1048576);
  concat3<<<12, 256, 0, stream>>>(bq, bk, bv, BQKV);
  packmask<<<1024, 256, 0, stream>>>(msk, MW);
  ln_bf16<<<8192, 256, 0, stream>>>(x, g1, be1, XN);
  gemm256<0, 0, 1><<<dim3(12, 32), 512, SMEM, stream>>>(XN, WQKV, BQKV, nullptr,
                                                        QKV, 8192, 3072, 1024);
  attn_fwd<<<2048, 256, 0, stream>>>(QKV, MW, AO);
  gemm256<0, 1, 0><<<dim3(4, 32), 512, SMEM, stream>>>(AO, WO, bo, x, X1, 8192,
                                                       1024, 1024);
  ln_bf16<<<8192, 256, 0, stream>>>(X1, g2, be2, XN);
  gemm256<1, 0, 1><<<dim3(16, 32), 512, SMEM, stream>>>(XN, W1, b1, nullptr, F1,
                                                        8192, 4096, 1024);
  gemm256<0, 1, 0><<<dim3(4, 32), 512, SMEM, stream>>>(F1, W2, b2, X1, out, 8192,
                                                       1024, 4096);
}